// Round 10
// baseline (225.258 us; speedup 1.0000x reference)
//
#include <hip/hip_runtime.h>

#define NB    32      // batch
#define CIN   512     // IN_CH
#define MID2  1024    // MAX_MID*2
#define MID   512     // MAX_MID
#define HW    4096    // 64*64

#define MLPB  512     // k_mlp blocks; 8 blocks/CU capacity * 256 CUs = 2048 >> 512
                      // -> all blocks co-resident -> spin barrier cannot deadlock

typedef float f32x4 __attribute__((ext_vector_type(4)));

// ---------------- Kernel 1: global average pool (R6 known-good) ----------
// 8192 blocks x 256 threads, two rows per block, 8 nt float4 loads in flight.
// Thread 2 of block 0 zeroes the k_mlp barrier counters (kernel-boundary
// ordering makes them visible to k_mlp; re-zeroed every call -> replay-safe).
__global__ __launch_bounds__(256, 8) void k_gap(const float* __restrict__ x,
                                                float* __restrict__ gap,
                                                unsigned int* cnt) {
    const int r0 = blockIdx.x * 2;
    const int t  = threadIdx.x;
    const f32x4* p0 = (const f32x4*)(x + (size_t)r0 * HW);
    const f32x4* p1 = (const f32x4*)(x + (size_t)(r0 + 1) * HW);
    float a0 = 0.f, a1 = 0.f;
#pragma unroll
    for (int i = 0; i < 4; ++i) {
        f32x4 u = __builtin_nontemporal_load(&p0[i * 256 + t]);
        f32x4 v = __builtin_nontemporal_load(&p1[i * 256 + t]);
        a0 += (u.x + u.y) + (u.z + u.w);
        a1 += (v.x + v.y) + (v.z + v.w);
    }
    for (int off = 32; off; off >>= 1) {
        a0 += __shfl_down(a0, off, 64);
        a1 += __shfl_down(a1, off, 64);
    }
    __shared__ float w0[4], w1[4];
    const int wid = t >> 6, lane = t & 63;
    if (lane == 0) { w0[wid] = a0; w1[wid] = a1; }
    __syncthreads();
    if (t == 0) gap[r0]     = ((w0[0] + w0[1]) + (w0[2] + w0[3])) * (1.0f / HW);
    if (t == 1) gap[r0 + 1] = ((w1[0] + w1[1]) + (w1[2] + w1[3])) * (1.0f / HW);
    if (blockIdx.x == 0 && t == 2) { cnt[0] = 0u; cnt[1] = 0u; }
}

// Device-scope arrive: every thread fences its stores, block joins, t0 adds.
__device__ __forceinline__ void barrier_arrive(unsigned int* c) {
    __threadfence();
    __syncthreads();
    if (threadIdx.x == 0)
        __hip_atomic_fetch_add(c, 1u, __ATOMIC_RELEASE, __HIP_MEMORY_SCOPE_AGENT);
}
// Wait until all MLPB blocks arrived, then acquire.
__device__ __forceinline__ void barrier_wait(unsigned int* c) {
    if (threadIdx.x == 0) {
        while (__hip_atomic_load(c, __ATOMIC_ACQUIRE, __HIP_MEMORY_SCOPE_AGENT)
               < (unsigned)MLPB) {
            __builtin_amdgcn_s_sleep(8);
        }
    }
    __syncthreads();
    __threadfence();
}

// ---------------- Kernel 2: fused fc1 -> barrier -> fc2 -> barrier -> mask --
// 512 blocks x 256 threads (2048 waves). Weight traffic stays spread over all
// CUs (R3 lesson). All FP orders fixed -> deterministic.
__global__ __launch_bounds__(256, 8) void k_mlp(const float* __restrict__ gap,
                                                const float* __restrict__ w1,
                                                const float* __restrict__ b1,
                                                const float* __restrict__ w2,
                                                const float* __restrict__ b2,
                                                float* h,
                                                float* scores,
                                                float* out,
                                                unsigned int* cnt) {
    const int t = threadIdx.x, wid = t >> 6, lane = t & 63;
    const int gwave = blockIdx.x * 4 + wid;           // 0 .. 2047

    // ---- Phase A: fc1 + ReLU, 16 outputs/wave in 4 groups of 4 ----
    {
        const int o0 = gwave * 16;                    // 0 .. 32752
        const int b  = o0 >> 10;
        const int j0 = o0 & (MID2 - 1);
        const float* g = gap + b * CIN + lane * 8;
        const float4 g0 = *(const float4*)g;
        const float4 g1 = *(const float4*)(g + 4);
#pragma unroll
        for (int grp = 0; grp < 4; ++grp) {
            float s[4];
#pragma unroll
            for (int r = 0; r < 4; ++r) {
                const float* w = w1 + (size_t)(j0 + grp * 4 + r) * CIN + lane * 8;
                const float4 a = *(const float4*)w;
                const float4 c = *(const float4*)(w + 4);
                s[r] = (a.x * g0.x + a.y * g0.y) + (a.z * g0.z + a.w * g0.w) +
                       (c.x * g1.x + c.y * g1.y) + (c.z * g1.z + c.w * g1.w);
            }
#pragma unroll
            for (int r = 0; r < 4; ++r)
                for (int off = 32; off; off >>= 1) s[r] += __shfl_down(s[r], off, 64);
            if (lane == 0) {
#pragma unroll
                for (int r = 0; r < 4; ++r) {
                    const int j = j0 + grp * 4 + r;
                    h[o0 + grp * 4 + r] = fmaxf(s[r] + b1[j], 0.f);
                }
            }
        }
    }
    barrier_arrive(&cnt[0]);
    barrier_wait(&cnt[0]);

    // ---- Phase B: fc2 + sigmoid, 8 outputs/wave in 2 groups of 4 ----
    {
        const int o0 = gwave * 8;                     // 0 .. 16376
        const int b  = o0 >> 9;
        const int m0 = o0 & (MID - 1);
        const float4* h4 = (const float4*)(h + b * MID2 + lane * 16);
        const float4 h0 = h4[0], h1 = h4[1], h2 = h4[2], h3 = h4[3];
#pragma unroll
        for (int grp = 0; grp < 2; ++grp) {
            float s[4];
#pragma unroll
            for (int r = 0; r < 4; ++r) {
                const float4* w = (const float4*)(w2 + (size_t)(m0 + grp * 4 + r) * MID2 + lane * 16);
                const float4 a = w[0], c = w[1], d = w[2], e = w[3];
                s[r] = (a.x * h0.x + a.y * h0.y) + (a.z * h0.z + a.w * h0.w) +
                       (c.x * h1.x + c.y * h1.y) + (c.z * h1.z + c.w * h1.w) +
                       (d.x * h2.x + d.y * h2.y) + (d.z * h2.z + d.w * h2.w) +
                       (e.x * h3.x + e.y * h3.y) + (e.z * h3.z + e.w * h3.w);
            }
#pragma unroll
            for (int r = 0; r < 4; ++r)
                for (int off = 32; off; off >>= 1) s[r] += __shfl_down(s[r], off, 64);
            if (lane == 0) {
#pragma unroll
                for (int r = 0; r < 4; ++r) {
                    const int m = o0 + grp * 4 + r;
                    const float v = s[r] + b2[m0 + grp * 4 + r];
                    scores[m] = 1.0f / (1.0f + __expf(-v));
                }
            }
        }
    }
    barrier_arrive(&cnt[1]);
    if (blockIdx.x >= NB) return;     // only mask blocks wait
    barrier_wait(&cnt[1]);

    // ---- Phase C: mean -> k -> threshold -> mask (blocks 0..31) ----
    const int b = blockIdx.x;
    __shared__ float srow[MID];
    __shared__ float red[4];
    __shared__ float thr;

    float s = 0.f;
#pragma unroll
    for (int i = 0; i < NB * MID / 256; ++i) s += scores[i * 256 + t];
    for (int off = 32; off; off >>= 1) s += __shfl_down(s, off, 64);
    if (lane == 0) red[wid] = s;

    const float v0 = scores[b * MID + t];
    const float v1 = scores[b * MID + t + 256];
    srow[t]       = v0;
    srow[t + 256] = v1;
    __syncthreads();

    const float tot = (red[0] + red[1]) + (red[2] + red[3]);
    const float mean = tot / (float)(NB * MID);
    const float scale = fminf(fmaxf(mean, 0.25f), 1.0f);
    int k = (int)ceilf((float)MID * scale);
    k = min(max(k, 128), MID);                        // k_min = max(4, 512/4) = 128

    const float4* srow4 = (const float4*)srow;
    int gt0 = 0, ge0 = 0, gt1 = 0, ge1 = 0;
    for (int i = 0; i < MID / 4; ++i) {
        const float4 u = srow4[i];    // uniform addr -> LDS broadcast
        gt0 += (u.x > v0) + (u.y > v0) + (u.z > v0) + (u.w > v0);
        ge0 += (u.x >= v0) + (u.y >= v0) + (u.z >= v0) + (u.w >= v0);
        gt1 += (u.x > v1) + (u.y > v1) + (u.z > v1) + (u.w > v1);
        ge1 += (u.x >= v1) + (u.y >= v1) + (u.z >= v1) + (u.w >= v1);
    }
    if (gt0 < k && ge0 >= k) thr = v0;  // tie-safe kth-largest selection
    if (gt1 < k && ge1 >= k) thr = v1;
    __syncthreads();
    out[b * MID + t]       = (v0 >= thr) ? 1.0f : 0.0f;
    out[b * MID + t + 256] = (v1 >= thr) ? 1.0f : 0.0f;
    if (b == 0 && t == 0) out[NB * MID] = (float)k;
}

extern "C" void kernel_launch(void* const* d_in, const int* in_sizes, int n_in,
                              void* d_out, int out_size, void* d_ws, size_t ws_size,
                              hipStream_t stream) {
    const float* x  = (const float*)d_in[0];
    const float* w1 = (const float*)d_in[1];
    const float* b1 = (const float*)d_in[2];
    const float* w2 = (const float*)d_in[3];
    const float* b2 = (const float*)d_in[4];
    float* out = (float*)d_out;

    float* gap    = (float*)d_ws;            // NB*CIN  = 16384 floats
    float* h      = gap + NB * CIN;          // NB*MID2 = 32768 floats
    float* scores = h + NB * MID2;           // NB*MID  = 16384 floats
    unsigned int* cnt = (unsigned int*)(scores + NB * MID);   // 2 counters

    k_gap<<<NB * CIN / 2, 256, 0, stream>>>(x, gap, cnt);
    k_mlp<<<MLPB,         256, 0, stream>>>(gap, w1, b1, w2, b2, h, scores, out, cnt);
}

// Round 11
// 110.953 us; speedup vs baseline: 2.0302x; 2.0302x over previous
//
#include <hip/hip_runtime.h>

#define NB    32      // batch
#define CIN   512     // IN_CH
#define MID2  1024    // MAX_MID*2
#define MID   512     // MAX_MID
#define HW    4096    // 64*64

#define MLPB  256     // k_mlp blocks: 1 block/CU -> co-residency guaranteed,
                      // low barrier contention (256 arrivals / 256 pollers)

typedef float f32x4 __attribute__((ext_vector_type(4)));

// ---------------- Kernel 1: global average pool (R6 known-good) ----------
// 8192 blocks x 256 threads, two rows per block, 8 nt float4 loads in flight.
// Thread 2 of block 0 zeroes the k_mlp barrier counter (kernel-boundary
// ordering makes it visible to k_mlp; re-zeroed every call -> replay-safe).
__global__ __launch_bounds__(256, 8) void k_gap(const float* __restrict__ x,
                                                float* __restrict__ gap,
                                                unsigned int* cnt) {
    const int r0 = blockIdx.x * 2;
    const int t  = threadIdx.x;
    const f32x4* p0 = (const f32x4*)(x + (size_t)r0 * HW);
    const f32x4* p1 = (const f32x4*)(x + (size_t)(r0 + 1) * HW);
    float a0 = 0.f, a1 = 0.f;
#pragma unroll
    for (int i = 0; i < 4; ++i) {
        f32x4 u = __builtin_nontemporal_load(&p0[i * 256 + t]);
        f32x4 v = __builtin_nontemporal_load(&p1[i * 256 + t]);
        a0 += (u.x + u.y) + (u.z + u.w);
        a1 += (v.x + v.y) + (v.z + v.w);
    }
    for (int off = 32; off; off >>= 1) {
        a0 += __shfl_down(a0, off, 64);
        a1 += __shfl_down(a1, off, 64);
    }
    __shared__ float w0[4], w1[4];
    const int wid = t >> 6, lane = t & 63;
    if (lane == 0) { w0[wid] = a0; w1[wid] = a1; }
    __syncthreads();
    if (t == 0) gap[r0]     = ((w0[0] + w0[1]) + (w0[2] + w0[3])) * (1.0f / HW);
    if (t == 1) gap[r0 + 1] = ((w1[0] + w1[1]) + (w1[2] + w1[3])) * (1.0f / HW);
    if (blockIdx.x == 0 && t == 2) { cnt[0] = 0u; cnt[1] = 0u; }
}

// Device barrier v2: release-add once per block; poll with RELAXED loads +
// long s_sleep backoff (no per-poll cache invalidation); ONE acquire fence
// after exit. Prior version's per-poll ACQUIRE caused a ~180us pathology.
__device__ __forceinline__ void dev_barrier(unsigned int* c) {
    __threadfence();                       // make this block's stores visible
    __syncthreads();
    if (threadIdx.x == 0) {
        __hip_atomic_fetch_add(c, 1u, __ATOMIC_RELEASE, __HIP_MEMORY_SCOPE_AGENT);
        while (__hip_atomic_load(c, __ATOMIC_RELAXED, __HIP_MEMORY_SCOPE_AGENT)
               < (unsigned)MLPB) {
            __builtin_amdgcn_s_sleep(32);  // ~0.85us backoff, decongests fabric
        }
    }
    __syncthreads();
    __builtin_amdgcn_fence(__ATOMIC_ACQUIRE, "agent");   // one acquire, not per poll
}

// ---------------- Kernel 2: fc1 + ReLU -> barrier -> fc2 + sigmoid ----------
// 256 blocks x 256 threads (1024 waves). Weights spread over all CUs (R3
// lesson). All FP orders fixed -> deterministic.
__global__ __launch_bounds__(256, 8) void k_mlp(const float* __restrict__ gap,
                                                const float* __restrict__ w1,
                                                const float* __restrict__ b1,
                                                const float* __restrict__ w2,
                                                const float* __restrict__ b2,
                                                float* h,
                                                float* scores,
                                                unsigned int* cnt) {
    const int t = threadIdx.x, wid = t >> 6, lane = t & 63;
    const int gwave = blockIdx.x * 4 + wid;           // 0 .. 1023

    // ---- Phase A: fc1 + ReLU, 32 outputs/wave in 8 groups of 4 ----
    {
        const int o0 = gwave * 32;                    // 0 .. 32736
        const int b  = o0 >> 10;
        const int j0 = o0 & (MID2 - 1);
        const float* g = gap + b * CIN + lane * 8;
        const float4 g0 = *(const float4*)g;
        const float4 g1 = *(const float4*)(g + 4);
#pragma unroll
        for (int grp = 0; grp < 8; ++grp) {
            float s[4];
#pragma unroll
            for (int r = 0; r < 4; ++r) {
                const float* w = w1 + (size_t)(j0 + grp * 4 + r) * CIN + lane * 8;
                const float4 a = *(const float4*)w;
                const float4 c = *(const float4*)(w + 4);
                s[r] = (a.x * g0.x + a.y * g0.y) + (a.z * g0.z + a.w * g0.w) +
                       (c.x * g1.x + c.y * g1.y) + (c.z * g1.z + c.w * g1.w);
            }
#pragma unroll
            for (int r = 0; r < 4; ++r)
                for (int off = 32; off; off >>= 1) s[r] += __shfl_down(s[r], off, 64);
            if (lane == 0) {
#pragma unroll
                for (int r = 0; r < 4; ++r) {
                    const int j = j0 + grp * 4 + r;
                    h[o0 + grp * 4 + r] = fmaxf(s[r] + b1[j], 0.f);
                }
            }
        }
    }
    dev_barrier(&cnt[0]);

    // ---- Phase B: fc2 + sigmoid, 16 outputs/wave in 4 groups of 4 ----
    {
        const int o0 = gwave * 16;                    // 0 .. 16368
        const int b  = o0 >> 9;
        const int m0 = o0 & (MID - 1);
        const float4* h4 = (const float4*)(h + b * MID2 + lane * 16);
        const float4 h0 = h4[0], h1 = h4[1], h2 = h4[2], h3 = h4[3];
#pragma unroll
        for (int grp = 0; grp < 4; ++grp) {
            float s[4];
#pragma unroll
            for (int r = 0; r < 4; ++r) {
                const float4* w = (const float4*)(w2 + (size_t)(m0 + grp * 4 + r) * MID2 + lane * 16);
                const float4 a = w[0], c = w[1], d = w[2], e = w[3];
                s[r] = (a.x * h0.x + a.y * h0.y) + (a.z * h0.z + a.w * h0.w) +
                       (c.x * h1.x + c.y * h1.y) + (c.z * h1.z + c.w * h1.w) +
                       (d.x * h2.x + d.y * h2.y) + (d.z * h2.z + d.w * h2.w) +
                       (e.x * h3.x + e.y * h3.y) + (e.z * h3.z + e.w * h3.w);
            }
#pragma unroll
            for (int r = 0; r < 4; ++r)
                for (int off = 32; off; off >>= 1) s[r] += __shfl_down(s[r], off, 64);
            if (lane == 0) {
#pragma unroll
                for (int r = 0; r < 4; ++r) {
                    const int m = o0 + grp * 4 + r;
                    const float v = s[r] + b2[m0 + grp * 4 + r];
                    scores[m] = 1.0f / (1.0f + __expf(-v));
                }
            }
        }
    }
}

// ---------------- Kernel 3: mean -> k -> threshold -> mask (R6) ----------
__global__ __launch_bounds__(512) void k_mask(const float* __restrict__ scores,
                                              float* __restrict__ out) {
    __shared__ float srow[MID];
    __shared__ float red[8];
    __shared__ float thr;
    const int b = blockIdx.x, t = threadIdx.x;

    float s = 0.f;
#pragma unroll
    for (int i = 0; i < NB * MID / 512; ++i) s += scores[i * 512 + t];
    for (int off = 32; off; off >>= 1) s += __shfl_down(s, off, 64);
    const int wid = t >> 6, lane = t & 63;
    if (lane == 0) red[wid] = s;

    const float v = scores[b * MID + t];
    srow[t] = v;
    __syncthreads();

    const float tot = ((red[0] + red[1]) + (red[2] + red[3])) +
                      ((red[4] + red[5]) + (red[6] + red[7]));
    const float mean = tot / (float)(NB * MID);
    const float scale = fminf(fmaxf(mean, 0.25f), 1.0f);
    int k = (int)ceilf((float)MID * scale);
    k = min(max(k, 128), MID);                        // k_min = max(4, 512/4) = 128

    const float4* srow4 = (const float4*)srow;
    int gt = 0, ge = 0;
    for (int i = 0; i < MID / 4; ++i) {
        const float4 u = srow4[i];    // uniform addr -> LDS broadcast
        gt += (u.x > v) + (u.y > v) + (u.z > v) + (u.w > v);
        ge += (u.x >= v) + (u.y >= v) + (u.z >= v) + (u.w >= v);
    }
    if (gt < k && ge >= k) thr = v;   // tie-safe kth-largest selection
    __syncthreads();
    out[b * MID + t] = (v >= thr) ? 1.0f : 0.0f;
    if (b == 0 && t == 0) out[NB * MID] = (float)k;
}

extern "C" void kernel_launch(void* const* d_in, const int* in_sizes, int n_in,
                              void* d_out, int out_size, void* d_ws, size_t ws_size,
                              hipStream_t stream) {
    const float* x  = (const float*)d_in[0];
    const float* w1 = (const float*)d_in[1];
    const float* b1 = (const float*)d_in[2];
    const float* w2 = (const float*)d_in[3];
    const float* b2 = (const float*)d_in[4];
    float* out = (float*)d_out;

    float* gap    = (float*)d_ws;            // NB*CIN  = 16384 floats
    float* h      = gap + NB * CIN;          // NB*MID2 = 32768 floats
    float* scores = h + NB * MID2;           // NB*MID  = 16384 floats
    unsigned int* cnt = (unsigned int*)(scores + NB * MID);   // 2 counters

    k_gap <<<NB * CIN / 2, 256, 0, stream>>>(x, gap, cnt);
    k_mlp <<<MLPB,         256, 0, stream>>>(gap, w1, b1, w2, b2, h, scores, cnt);
    k_mask<<<NB,           512, 0, stream>>>(scores, out);
}

// Round 12
// 67.400 us; speedup vs baseline: 3.3421x; 1.6462x over previous
//
#include <hip/hip_runtime.h>

#define NB    32      // batch
#define CIN   512     // IN_CH
#define MID2  1024    // MAX_MID*2
#define MID   512     // MAX_MID
#define HW    4096    // 64*64

typedef float f32x4 __attribute__((ext_vector_type(4)));

// ---------------- Kernel 1: global average pool ----------------
// 8192 blocks x 256 threads, TWO rows per block: 8 independent nontemporal
// float4 loads per thread (32 VGPR of data), __launch_bounds__(256,8) pins
// VGPR <= 64 so occupancy hits 32 waves/CU -- max memory-level parallelism.
// Best measured GAP configuration (R6: total 67.3 us).
__global__ __launch_bounds__(256, 8) void k_gap(const float* __restrict__ x,
                                                float* __restrict__ gap) {
    const int r0 = blockIdx.x * 2;
    const int t  = threadIdx.x;
    const f32x4* p0 = (const f32x4*)(x + (size_t)r0 * HW);
    const f32x4* p1 = (const f32x4*)(x + (size_t)(r0 + 1) * HW);
    float a0 = 0.f, a1 = 0.f;
#pragma unroll
    for (int i = 0; i < 4; ++i) {
        f32x4 u = __builtin_nontemporal_load(&p0[i * 256 + t]);
        f32x4 v = __builtin_nontemporal_load(&p1[i * 256 + t]);
        a0 += (u.x + u.y) + (u.z + u.w);
        a1 += (v.x + v.y) + (v.z + v.w);
    }
    for (int off = 32; off; off >>= 1) {
        a0 += __shfl_down(a0, off, 64);
        a1 += __shfl_down(a1, off, 64);
    }
    __shared__ float w0[4], w1[4];
    const int wid = t >> 6, lane = t & 63;
    if (lane == 0) { w0[wid] = a0; w1[wid] = a1; }
    __syncthreads();
    if (t == 0) gap[r0]     = ((w0[0] + w0[1]) + (w0[2] + w0[3])) * (1.0f / HW);
    if (t == 1) gap[r0 + 1] = ((w1[0] + w1[1]) + (w1[2] + w1[3])) * (1.0f / HW);
}

// ---------------- Kernel 2: fc1 + ReLU ----------------
// 2048 blocks x 256 threads; each wave computes 4 consecutive outputs of the
// same batch row, reusing the gap slice held in registers.
__global__ __launch_bounds__(256) void k_fc1(const float* __restrict__ gap,
                                             const float* __restrict__ w1,
                                             const float* __restrict__ b1,
                                             float* __restrict__ h) {
    const int wid = threadIdx.x >> 6, lane = threadIdx.x & 63;
    const int o4 = (blockIdx.x * 4 + wid) * 4;        // first of 4 outputs
    const int b  = o4 >> 10;                          // o4 / MID2
    const int j0 = o4 & (MID2 - 1);
    const float* g = gap + b * CIN + lane * 8;
    const float4 g0 = *(const float4*)g;
    const float4 g1 = *(const float4*)(g + 4);
    float s[4];
#pragma unroll
    for (int r = 0; r < 4; ++r) {
        const float* w = w1 + (size_t)(j0 + r) * CIN + lane * 8;
        const float4 a = *(const float4*)w;
        const float4 c = *(const float4*)(w + 4);
        s[r] = (a.x * g0.x + a.y * g0.y) + (a.z * g0.z + a.w * g0.w) +
               (c.x * g1.x + c.y * g1.y) + (c.z * g1.z + c.w * g1.w);
    }
#pragma unroll
    for (int r = 0; r < 4; ++r)
        for (int off = 32; off; off >>= 1) s[r] += __shfl_down(s[r], off, 64);
    if (lane == 0) {
#pragma unroll
        for (int r = 0; r < 4; ++r) h[o4 + r] = fmaxf(s[r] + b1[j0 + r], 0.f);
    }
}

// ---------------- Kernel 3: fc2 + sigmoid ----------------
// 1024 blocks x 256 threads; each wave computes 4 consecutive outputs,
// reusing the h slice (16 floats/lane) across the 4 weight rows.
__global__ __launch_bounds__(256) void k_fc2(const float* __restrict__ h,
                                             const float* __restrict__ w2,
                                             const float* __restrict__ b2,
                                             float* __restrict__ scores) {
    const int wid = threadIdx.x >> 6, lane = threadIdx.x & 63;
    const int o4 = (blockIdx.x * 4 + wid) * 4;        // first of 4 outputs
    const int b  = o4 >> 9;                           // o4 / MID
    const int m0 = o4 & (MID - 1);
    const float4* h4 = (const float4*)(h + b * MID2 + lane * 16);
    const float4 h0 = h4[0], h1 = h4[1], h2 = h4[2], h3 = h4[3];
    float s[4];
#pragma unroll
    for (int r = 0; r < 4; ++r) {
        const float4* w = (const float4*)(w2 + (size_t)(m0 + r) * MID2 + lane * 16);
        const float4 a = w[0], c = w[1], d = w[2], e = w[3];
        s[r] = (a.x * h0.x + a.y * h0.y) + (a.z * h0.z + a.w * h0.w) +
               (c.x * h1.x + c.y * h1.y) + (c.z * h1.z + c.w * h1.w) +
               (d.x * h2.x + d.y * h2.y) + (d.z * h2.z + d.w * h2.w) +
               (e.x * h3.x + e.y * h3.y) + (e.z * h3.z + e.w * h3.w);
    }
#pragma unroll
    for (int r = 0; r < 4; ++r)
        for (int off = 32; off; off >>= 1) s[r] += __shfl_down(s[r], off, 64);
    if (lane == 0) {
#pragma unroll
        for (int r = 0; r < 4; ++r) {
            const float v = s[r] + b2[m0 + r];
            scores[o4 + r] = 1.0f / (1.0f + __expf(-v));
        }
    }
}

// ---------------- Kernel 4: fused mean->k->threshold->mask ----------------
// 32 blocks x 512 threads. Every block redundantly computes the global mean
// (identical FP order -> identical k in all blocks, deterministic), then
// rank-count selection for its own row. Tie-safe: the k-th largest value v
// satisfies count(>v) < k <= count(>=v).
__global__ __launch_bounds__(512) void k_mask(const float* __restrict__ scores,
                                              float* __restrict__ out) {
    __shared__ float srow[MID];
    __shared__ float red[8];
    __shared__ float thr;
    const int b = blockIdx.x, t = threadIdx.x;

    float s = 0.f;
#pragma unroll
    for (int i = 0; i < NB * MID / 512; ++i) s += scores[i * 512 + t];
    for (int off = 32; off; off >>= 1) s += __shfl_down(s, off, 64);
    const int wid = t >> 6, lane = t & 63;
    if (lane == 0) red[wid] = s;

    const float v = scores[b * MID + t];
    srow[t] = v;
    __syncthreads();

    const float tot = ((red[0] + red[1]) + (red[2] + red[3])) +
                      ((red[4] + red[5]) + (red[6] + red[7]));
    const float mean = tot / (float)(NB * MID);
    const float scale = fminf(fmaxf(mean, 0.25f), 1.0f);
    int k = (int)ceilf((float)MID * scale);
    k = min(max(k, 128), MID);                        // k_min = max(4, 512/4) = 128

    const float4* srow4 = (const float4*)srow;
    int gt = 0, ge = 0;
    for (int i = 0; i < MID / 4; ++i) {
        const float4 u = srow4[i];    // uniform addr -> LDS broadcast
        gt += (u.x > v) + (u.y > v) + (u.z > v) + (u.w > v);
        ge += (u.x >= v) + (u.y >= v) + (u.z >= v) + (u.w >= v);
    }
    if (gt < k && ge >= k) thr = v;   // all satisfying threads hold the same value
    __syncthreads();
    out[b * MID + t] = (v >= thr) ? 1.0f : 0.0f;
    if (b == 0 && t == 0) out[NB * MID] = (float)k;
}

extern "C" void kernel_launch(void* const* d_in, const int* in_sizes, int n_in,
                              void* d_out, int out_size, void* d_ws, size_t ws_size,
                              hipStream_t stream) {
    const float* x  = (const float*)d_in[0];
    const float* w1 = (const float*)d_in[1];
    const float* b1 = (const float*)d_in[2];
    const float* w2 = (const float*)d_in[3];
    const float* b2 = (const float*)d_in[4];
    float* out = (float*)d_out;

    float* gap    = (float*)d_ws;            // NB*CIN  = 16384 floats
    float* h      = gap + NB * CIN;          // NB*MID2 = 32768 floats
    float* scores = h + NB * MID2;           // NB*MID  = 16384 floats

    k_gap <<<NB * CIN / 2,       256, 0, stream>>>(x, gap);
    k_fc1 <<<NB * MID2 / (4*4),  256, 0, stream>>>(gap, w1, b1, h);
    k_fc2 <<<NB * MID  / (4*4),  256, 0, stream>>>(h, w2, b2, scores);
    k_mask<<<NB,                 512, 0, stream>>>(scores, out);
}